// Round 5
// baseline (343.432 us; speedup 1.0000x reference)
//
#include <hip/hip_runtime.h>
#include <math.h>

#define G 5000
#define IN 64
#define D 128
#define E 240000
#define EG (E + G)
#define SLOPE 0.2f
#define GD (G * D)
#define NB_M 1250   // mlp1 blocks (512 rows each)

typedef float fv4 __attribute__((ext_vector_type(4)));

__device__ __forceinline__ float leaky(float v) { return v >= 0.f ? v : SLOPE * v; }

// ---------------- zero int buffer ----------------
__global__ __launch_bounds__(256) void k_zero32(int* __restrict__ p, int n) {
    int i = blockIdx.x * 256 + threadIdx.x;
    if (i < n) p[i] = 0;
}

// ---------------- K1: per-gene linear + relu (wave/gene, float4, 2 rows/iter) ----------------
__global__ __launch_bounds__(256) void k_pergene(const float* __restrict__ x,
                                                 const float* __restrict__ Win,
                                                 const float* __restrict__ bin,
                                                 float* __restrict__ h) {
    int g = blockIdx.x * 4 + (threadIdx.x >> 6);
    int lane = threadIdx.x & 63;
    int half = lane >> 5, l5 = lane & 31;
    float xv = x[g * IN + lane];
    const float* W = Win + (size_t)g * (IN * D) + half * D + l5 * 4;
    fv4 acc = {0.f, 0.f, 0.f, 0.f};
#pragma unroll 8
    for (int ip = 0; ip < 32; ++ip) {
        float xi = __shfl(xv, 2 * ip + half);
        fv4 w4 = __builtin_nontemporal_load((const fv4*)(W + (size_t)ip * (2 * D)));
        acc.x = fmaf(xi, w4.x, acc.x);
        acc.y = fmaf(xi, w4.y, acc.y);
        acc.z = fmaf(xi, w4.z, acc.z);
        acc.w = fmaf(xi, w4.w, acc.w);
    }
    acc.x += __shfl_xor(acc.x, 32);
    acc.y += __shfl_xor(acc.y, 32);
    acc.z += __shfl_xor(acc.z, 32);
    acc.w += __shfl_xor(acc.w, 32);
    if (half == 0) {
        float4 b4 = *(const float4*)(bin + g * D + l5 * 4);
        float4 o = { fmaxf(acc.x + b4.x, 0.f), fmaxf(acc.y + b4.y, 0.f),
                     fmaxf(acc.z + b4.z, 0.f), fmaxf(acc.w + b4.w, 0.f) };
        *(float4*)(h + g * D + l5 * 4) = o;
    }
}

// ---------------- K2: xl = h@Wl + bl ; xr = h@Wr + br (round-2 verbatim) ----------------
#define GPB 20
__global__ __launch_bounds__(128) void k_xlxr(const float* __restrict__ h,
                                              const float* __restrict__ Wl,
                                              const float* __restrict__ bl,
                                              const float* __restrict__ Wr,
                                              const float* __restrict__ br,
                                              float* __restrict__ xl,
                                              float* __restrict__ xr) {
    int g0 = blockIdx.x * GPB;
    int d = threadIdx.x;
    __shared__ float hs[GPB][D];
    for (int j = 0; j < GPB; ++j) hs[j][d] = h[(g0 + j) * D + d];
    __syncthreads();
    float al[GPB], ar[GPB];
    float blv = bl[d], brv = br[d];
#pragma unroll
    for (int j = 0; j < GPB; ++j) { al[j] = blv; ar[j] = brv; }
    for (int k = 0; k < D; ++k) {
        float wl = Wl[k * D + d];
        float wr = Wr[k * D + d];
#pragma unroll
        for (int j = 0; j < GPB; ++j) {
            al[j] = fmaf(hs[j][k], wl, al[j]);
            ar[j] = fmaf(hs[j][k], wr, ar[j]);
        }
    }
    for (int j = 0; j < GPB; ++j) {
        xl[(g0 + j) * D + d] = al[j];
        xr[(g0 + j) * D + d] = ar[j];
    }
}

// ---------------- K3a: histogram ----------------
__global__ __launch_bounds__(256) void k_hist(const int* __restrict__ dstA,
                                              int* __restrict__ cnt) {
    int i = blockIdx.x * 256 + threadIdx.x;
    if (i >= EG) return;
    int t = (i < E) ? dstA[i] : i - E;
    atomicAdd(&cnt[t], 1);
}

// ---------------- K3b: exclusive scan (single block) ----------------
__global__ __launch_bounds__(256) void k_scan(const int* __restrict__ cnt,
                                              int* __restrict__ rowptr,
                                              int* __restrict__ cursor) {
    __shared__ int ssum[256];
    int tid = threadIdx.x;
    const int CH = (G + 255) / 256;   // 20
    int base = tid * CH;
    int s = 0;
    for (int k = 0; k < CH; ++k) { int idx = base + k; if (idx < G) s += cnt[idx]; }
    ssum[tid] = s;
    __syncthreads();
    for (int off = 1; off < 256; off <<= 1) {
        int v = ssum[tid];
        int add = (tid >= off) ? ssum[tid - off] : 0;
        __syncthreads();
        ssum[tid] = v + add;
        __syncthreads();
    }
    int run = (tid == 0) ? 0 : ssum[tid - 1];
    for (int k = 0; k < CH; ++k) {
        int idx = base + k;
        if (idx < G) { rowptr[idx] = run; cursor[idx] = run; run += cnt[idx]; }
    }
    if (tid == 255) rowptr[G] = run;   // == EG
}

// ---------------- K3c: bucket edges by destination ----------------
__global__ __launch_bounds__(256) void k_bucket(const int* __restrict__ srcA,
                                                const int* __restrict__ dstA,
                                                int* __restrict__ cursor,
                                                int* __restrict__ ssrc) {
    int i = blockIdx.x * 256 + threadIdx.x;
    if (i >= EG) return;
    int s, t;
    if (i < E) { s = srcA[i]; t = dstA[i]; }
    else { s = i - E; t = s; }
    int pos = atomicAdd(&cursor[t], 1);
    ssrc[pos] = s;
}

// ---------------- K4: GAT aggregation, one wave per destination (round-2 verbatim) ----------------
__global__ __launch_bounds__(256) void k_agg(const int* __restrict__ rowptr,
                                             const int* __restrict__ ssrc,
                                             const float* __restrict__ xl,
                                             const float* __restrict__ xr,
                                             const float* __restrict__ att,
                                             const float* __restrict__ bias,
                                             float* __restrict__ f) {
    int t = (blockIdx.x * 256 + threadIdx.x) >> 6;
    int lane = threadIdx.x & 63;
    if (t >= G) return;
    float2 a  = *(const float2*)(att + lane * 2);
    float2 r2 = *(const float2*)(xr + t * D + lane * 2);
    float2 acc = { 0.f, 0.f };
    float z = 0.f;
    int e0 = rowptr[t], e1 = rowptr[t + 1];
    for (int idx = e0; idx < e1; ++idx) {
        int s = ssrc[idx];
        float2 l2 = *(const float2*)(xl + s * D + lane * 2);
        float v = leaky(l2.x + r2.x) * a.x + leaky(l2.y + r2.y) * a.y;
#pragma unroll
        for (int off = 32; off; off >>= 1) v += __shfl_xor(v, off);
        float w = expf(v);
        z += w;
        acc.x = fmaf(w, l2.x, acc.x);
        acc.y = fmaf(w, l2.y, acc.y);
    }
    float2 b2 = *(const float2*)(bias + lane * 2);
    float inv = 1.f / z;
    float2 o = { leaky(acc.x * inv + b2.x), leaky(acc.y * inv + b2.y) };
    *(float2*)(f + t * D + lane * 2) = o;
}

// ---------------- K5: MLP layer 1 (float4, 2 rows/iter, 512 rows/block, NT) ----------------
__global__ __launch_bounds__(256) void k_mlp1(const float* __restrict__ f,
                                              const float* __restrict__ W1,
                                              float* __restrict__ partials) {
    int w = threadIdx.x >> 6, lane = threadIdx.x & 63;
    int half = lane >> 5, l5 = lane & 31;
    int r0 = blockIdx.x * 512;
    fv4 acc = {0.f, 0.f, 0.f, 0.f};
#pragma unroll 8
    for (int k = 0; k < 64; ++k) {
        int row = r0 + 2 * (w + 4 * k);
        float f0 = f[row], f1 = f[row + 1];
        float fv = half ? f1 : f0;
        const float* Wp = W1 + (size_t)row * D + half * D + l5 * 4;
        fv4 w4 = __builtin_nontemporal_load((const fv4*)Wp);
        acc.x = fmaf(fv, w4.x, acc.x);
        acc.y = fmaf(fv, w4.y, acc.y);
        acc.z = fmaf(fv, w4.z, acc.z);
        acc.w = fmaf(fv, w4.w, acc.w);
    }
    acc.x += __shfl_xor(acc.x, 32);
    acc.y += __shfl_xor(acc.y, 32);
    acc.z += __shfl_xor(acc.z, 32);
    acc.w += __shfl_xor(acc.w, 32);
    __shared__ float4 red[4][32];
    if (half == 0) red[w][l5] = (float4){acc.x, acc.y, acc.z, acc.w};
    __syncthreads();
    if (w == 0 && half == 0) {
        float4 s0 = red[0][l5], s1 = red[1][l5], s2 = red[2][l5], s3 = red[3][l5];
        float4 s = { s0.x + s1.x + s2.x + s3.x, s0.y + s1.y + s2.y + s3.y,
                     s0.z + s1.z + s2.z + s3.z, s0.w + s1.w + s2.w + s3.w };
        *(float4*)(partials + blockIdx.x * D + l5 * 4) = s;
    }
}

// ---------------- K6: reduce partials + relu + dot W2 ----------------
__global__ __launch_bounds__(256) void k_final(const float* __restrict__ partials,
                                               const float* __restrict__ b1,
                                               const float* __restrict__ W2,
                                               const float* __restrict__ b2,
                                               float* __restrict__ out) {
    int tid = threadIdx.x;
    int j = tid & 127, seg = tid >> 7;
    float s = 0.f;
    for (int b = seg; b < NB_M; b += 2) s += partials[b * D + j];
    __shared__ float red[256];
    red[tid] = s;
    __syncthreads();
    if (tid < 128) {
        float tot = red[tid] + red[128 + tid];
        float h1 = fmaxf(tot + b1[tid], 0.f);
        red[tid] = h1 * W2[tid];
    }
    __syncthreads();
    if (tid == 0) {
        float o = b2[0];
        for (int k = 0; k < 128; ++k) o += red[k];
        out[0] = o;
    }
}

extern "C" void kernel_launch(void* const* d_in, const int* in_sizes, int n_in,
                              void* d_out, int out_size, void* d_ws, size_t ws_size,
                              hipStream_t stream) {
    const float* x    = (const float*)d_in[0];
    const int*   ei   = (const int*)d_in[1];
    const float* Win  = (const float*)d_in[2];
    const float* bin  = (const float*)d_in[3];
    const float* Wl   = (const float*)d_in[4];
    const float* bl   = (const float*)d_in[5];
    const float* Wr   = (const float*)d_in[6];
    const float* br   = (const float*)d_in[7];
    const float* att  = (const float*)d_in[8];
    const float* bias = (const float*)d_in[9];
    const float* W1   = (const float*)d_in[10];
    const float* b1   = (const float*)d_in[11];
    const float* W2   = (const float*)d_in[12];
    const float* b2   = (const float*)d_in[13];
    float* out = (float*)d_out;

    float* ws       = (float*)d_ws;
    float* h        = ws;                  // GD
    float* xl       = h  + GD;             // GD
    float* xr       = xl + GD;             // GD
    float* f        = xr + GD;             // GD
    float* partials = f  + GD;             // NB_M * D
    int*   ssrc     = (int*)(partials + (size_t)NB_M * D);  // EG
    int*   cnt      = ssrc + EG;           // G
    int*   rowptr   = cnt + G;             // G+1
    int*   cursor   = rowptr + G + 1;      // G

    const int* srcA = ei;
    const int* dstA = ei + E;

    k_zero32<<<(G + 255) / 256, 256, 0, stream>>>(cnt, G);
    k_pergene<<<G / 4, 256, 0, stream>>>(x, Win, bin, h);
    k_xlxr<<<G / GPB, 128, 0, stream>>>(h, Wl, bl, Wr, br, xl, xr);
    k_hist<<<(EG + 255) / 256, 256, 0, stream>>>(dstA, cnt);
    k_scan<<<1, 256, 0, stream>>>(cnt, rowptr, cursor);
    k_bucket<<<(EG + 255) / 256, 256, 0, stream>>>(srcA, dstA, cursor, ssrc);
    k_agg<<<(G * 64 + 255) / 256, 256, 0, stream>>>(rowptr, ssrc, xl, xr, att, bias, f);
    k_mlp1<<<NB_M, 256, 0, stream>>>(f, W1, partials);
    k_final<<<1, 256, 0, stream>>>(partials, b1, W2, b2, out);
}